// Round 5
// baseline (182.411 us; speedup 1.0000x reference)
//
#include <hip/hip_runtime.h>

typedef __bf16 bf16_t;
typedef bf16_t bf16x8 __attribute__((ext_vector_type(8)));
typedef bf16_t bf16x4 __attribute__((ext_vector_type(4)));
typedef float f32x4 __attribute__((ext_vector_type(4)));

// ---------------- fp32 -> bf16 convert, all three tensors in one launch ----------------
__global__ void f2b_all(const float* __restrict__ x, const float* __restrict__ wq,
                        const float* __restrict__ wp,
                        bf16_t* __restrict__ xb, bf16_t* __restrict__ wqb,
                        bf16_t* __restrict__ wpb) {
    int i = blockIdx.x * blockDim.x + threadIdx.x;
    const float* src; bf16_t* dst; int off;
    if (i < 98304)       { src = x;  dst = xb;  off = i; }
    else if (i < 540672) { src = wq; dst = wqb; off = i - 98304; }
    else                 { src = wp; dst = wpb; off = i - 540672; }
    f32x4 v = reinterpret_cast<const f32x4*>(src)[off];
    bf16x4 o = { (bf16_t)v[0], (bf16_t)v[1], (bf16_t)v[2], (bf16_t)v[3] };
    reinterpret_cast<bf16x4*>(dst)[off] = o;
}

// ---------------- bf16 GEMM: C = A * B^T (+bias), 64x64 tile, BK=64, padded LDS ----------------
template <typename OUT_T, bool HAS_BIAS>
__global__ __launch_bounds__(256) void gemm_bt(
    const bf16_t* __restrict__ A, const bf16_t* __restrict__ B,
    OUT_T* __restrict__ C, const float* __restrict__ bias,
    int K, int lda, int ldb, int ldc)
{
    const int m0 = blockIdx.x * 64;
    const int n0 = blockIdx.y * 64;

    __shared__ __align__(16) bf16_t As[64][72];
    __shared__ __align__(16) bf16_t Bs[64][72];

    const int tid  = threadIdx.x;
    const int lane = tid & 63;
    const int wave = tid >> 6;

    f32x4 acc[4] = {};

    for (int k0 = 0; k0 < K; k0 += 64) {
#pragma unroll
        for (int c = 0; c < 2; ++c) {
            const int chunk = c * 256 + tid;
            const int row = chunk >> 3;
            const int off = (chunk & 7) * 8;
            *reinterpret_cast<uint4*>(&As[row][off]) =
                *reinterpret_cast<const uint4*>(&A[(long)(m0 + row) * lda + k0 + off]);
            *reinterpret_cast<uint4*>(&Bs[row][off]) =
                *reinterpret_cast<const uint4*>(&B[(long)(n0 + row) * ldb + k0 + off]);
        }
        __syncthreads();
#pragma unroll
        for (int ks = 0; ks < 64; ks += 32) {
            bf16x8 af = *reinterpret_cast<const bf16x8*>(&As[wave * 16 + (lane & 15)][(lane >> 4) * 8 + ks]);
#pragma unroll
            for (int nf = 0; nf < 4; ++nf) {
                bf16x8 bfr = *reinterpret_cast<const bf16x8*>(&Bs[nf * 16 + (lane & 15)][(lane >> 4) * 8 + ks]);
                acc[nf] = __builtin_amdgcn_mfma_f32_16x16x32_bf16(af, bfr, acc[nf], 0, 0, 0);
            }
        }
        __syncthreads();
    }

    const int crow0 = m0 + wave * 16 + (lane >> 4) * 4;
    const int ccol0 = n0 + (lane & 15);
#pragma unroll
    for (int nf = 0; nf < 4; ++nf) {
        const int col = ccol0 + nf * 16;
        const float bv = HAS_BIAS ? bias[col] : 0.0f;
#pragma unroll
        for (int v = 0; v < 4; ++v) {
            C[(long)(crow0 + v) * ldc + col] = (OUT_T)(acc[nf][v] + bv);
        }
    }
}

// ---------------- fused S = softmax((q/8) k^T) ----------------
__global__ __launch_bounds__(256) void qk_softmax(
    const bf16_t* __restrict__ qkv,   // [B,256,2304]
    float* __restrict__ probs)        // [24,256,256]
{
    const int bh = blockIdx.y;
    const int b = bh / 12, h = bh % 12;
    const int m0 = blockIdx.x * 64;
    const bf16_t* qbase = qkv + (long)b * 589824 + h * 64;
    const bf16_t* kbase = qkv + (long)b * 589824 + 768 + h * 64;

    __shared__ __align__(16) bf16_t Qs[64][72];
    __shared__ __align__(16) bf16_t Ks[256][72];

    const int t = threadIdx.x;
#pragma unroll
    for (int c = 0; c < 2; ++c) {
        const int chunk = c * 256 + t;
        const int row = chunk >> 3, off = (chunk & 7) * 8;
        *reinterpret_cast<uint4*>(&Qs[row][off]) =
            *reinterpret_cast<const uint4*>(qbase + (long)(m0 + row) * 2304 + off);
    }
#pragma unroll
    for (int c = 0; c < 8; ++c) {
        const int chunk = c * 256 + t;
        const int row = chunk >> 3, off = (chunk & 7) * 8;
        *reinterpret_cast<uint4*>(&Ks[row][off]) =
            *reinterpret_cast<const uint4*>(kbase + (long)row * 2304 + off);
    }
    __syncthreads();

    const int lane = t & 63, wave = t >> 6;
    f32x4 acc[16] = {};
#pragma unroll
    for (int ks = 0; ks < 64; ks += 32) {
        bf16x8 af = *reinterpret_cast<const bf16x8*>(&Qs[wave * 16 + (lane & 15)][(lane >> 4) * 8 + ks]);
#pragma unroll
        for (int nf = 0; nf < 16; ++nf) {
            bf16x8 bfr = *reinterpret_cast<const bf16x8*>(&Ks[nf * 16 + (lane & 15)][(lane >> 4) * 8 + ks]);
            acc[nf] = __builtin_amdgcn_mfma_f32_16x16x32_bf16(af, bfr, acc[nf], 0, 0, 0);
        }
    }

    float inv[4];
#pragma unroll
    for (int v = 0; v < 4; ++v) {
        float mm = -1e30f;
#pragma unroll
        for (int nf = 0; nf < 16; ++nf) { acc[nf][v] *= 0.125f; mm = fmaxf(mm, acc[nf][v]); }
#pragma unroll
        for (int o = 1; o < 16; o <<= 1) mm = fmaxf(mm, __shfl_xor(mm, o));
        float s = 0.0f;
#pragma unroll
        for (int nf = 0; nf < 16; ++nf) { float e = __expf(acc[nf][v] - mm); acc[nf][v] = e; s += e; }
#pragma unroll
        for (int o = 1; o < 16; o <<= 1) s += __shfl_xor(s, o);
        inv[v] = 1.0f / s;
    }

    float* prow = probs + ((long)bh * 256 + m0 + wave * 16 + (lane >> 4) * 4) * 256 + (lane & 15);
#pragma unroll
    for (int nf = 0; nf < 16; ++nf) {
#pragma unroll
        for (int v = 0; v < 4; ++v) {
            prow[(long)v * 256 + nf * 16] = acc[nf][v] * inv[v];
        }
    }
}

// ---------------- fused: oh[b,i,c] = sum_j attn * (v + d)  (round-3 structure) ----------------
__global__ __launch_bounds__(256) void attnd_kernel(
    const float* __restrict__ attn,   // [24,256,256]
    const bf16_t* __restrict__ qkv,   // [B,256,2304]
    const float* __restrict__ d,      // [B,256,256,768]
    bf16_t* __restrict__ oh)          // [B,256,768]
{
    const int bi = blockIdx.x;
    const int b  = bi >> 8;
    const int i  = bi & 255;
    const int cc = blockIdx.y;
    const int t  = threadIdx.x;
    const int lane = t & 63, wave = t >> 6;

    __shared__ float attn_s[4 * 257];
    __shared__ f32x4 partial[3][64];

#pragma unroll
    for (int q = 0; q < 4; ++q) {
        attn_s[q * 257 + t] = attn[(((long)(b * 12 + cc * 4 + q)) * 256 + i) * 256 + t];
    }
    __syncthreads();

    const int c0 = cc * 256 + lane * 4;
    const float* arow = attn_s + (lane >> 4) * 257;
    const int jb = wave * 64;
    const f32x4* dp = reinterpret_cast<const f32x4*>(d + (long)bi * 196608 + (long)jb * 768 + c0);
    const bf16_t* vp = qkv + (long)b * 589824 + (long)jb * 2304 + 1536 + c0;

    f32x4 acc = {};
#pragma unroll 8
    for (int jj = 0; jj < 64; ++jj) {
        f32x4 dv = __builtin_nontemporal_load(dp + (long)jj * 192);
        bf16x4 vv = *reinterpret_cast<const bf16x4*>(vp + (long)jj * 2304);
        float a = arow[jb + jj];
        acc[0] = fmaf(a, dv[0] + (float)vv[0], acc[0]);
        acc[1] = fmaf(a, dv[1] + (float)vv[1], acc[1]);
        acc[2] = fmaf(a, dv[2] + (float)vv[2], acc[2]);
        acc[3] = fmaf(a, dv[3] + (float)vv[3], acc[3]);
    }

    if (wave) partial[wave - 1][lane] = acc;
    __syncthreads();
    if (wave == 0) {
        acc += partial[0][lane] + partial[1][lane] + partial[2][lane];
        bf16x4 o = { (bf16_t)acc[0], (bf16_t)acc[1], (bf16_t)acc[2], (bf16_t)acc[3] };
        *reinterpret_cast<bf16x4*>(oh + (long)bi * 768 + c0) = o;
    }
}

// ---------------- launch ----------------
extern "C" void kernel_launch(void* const* d_in, const int* in_sizes, int n_in,
                              void* d_out, int out_size, void* d_ws, size_t ws_size,
                              hipStream_t stream) {
    const float* x      = (const float*)d_in[0];
    const float* d      = (const float*)d_in[1];
    const float* w_qkv  = (const float*)d_in[2];
    const float* w_proj = (const float*)d_in[3];
    const float* b_proj = (const float*)d_in[4];
    float* out = (float*)d_out;

    char* ws = (char*)d_ws;
    bf16_t* xb    = (bf16_t*)(ws);
    bf16_t* wqb   = (bf16_t*)(ws + 786432);
    bf16_t* wpb   = (bf16_t*)(ws + 4325376);
    bf16_t* qkvb  = (bf16_t*)(ws + 5505024);
    float*  probs = (float*)(ws + 7864320);
    bf16_t* oh    = (bf16_t*)(ws + 14155776);
    bf16_t* oh2   = (bf16_t*)(ws + 14942208);   // diagnostic duplicate output

    f2b_all<<<2688, 256, 0, stream>>>(x, w_qkv, w_proj, xb, wqb, wpb);

    gemm_bt<bf16_t, false><<<dim3(8, 36), 256, 0, stream>>>(
        xb, wqb, qkvb, nullptr, 768, 768, 768, 2304);

    qk_softmax<<<dim3(4, 24), 256, 0, stream>>>(qkvb, probs);

    // real attnd
    attnd_kernel<<<dim3(512, 3), 256, 0, stream>>>(probs, qkvb, d, oh);
    // DIAGNOSTIC: duplicate attnd into scratch — dur_us delta vs 119.9 = attnd cost
    attnd_kernel<<<dim3(512, 3), 256, 0, stream>>>(probs, qkvb, d, oh2);

    gemm_bt<float, true><<<dim3(8, 12), 256, 0, stream>>>(
        oh, wpb, out, b_proj, 768, 768, 768, 768);
}

// Round 6
// 103.038 us; speedup vs baseline: 1.7703x; 1.7703x over previous
//
#include <hip/hip_runtime.h>

typedef __bf16 bf16_t;
typedef bf16_t bf16x8 __attribute__((ext_vector_type(8)));
typedef bf16_t bf16x4 __attribute__((ext_vector_type(4)));
typedef float f32x4 __attribute__((ext_vector_type(4)));

// load 8 contiguous elements as bf16x8 (fp32 source converts in-register)
__device__ inline bf16x8 ld8(const float* p) {
    f32x4 a = *reinterpret_cast<const f32x4*>(p);
    f32x4 b = *reinterpret_cast<const f32x4*>(p + 4);
    bf16x8 r = { (bf16_t)a[0], (bf16_t)a[1], (bf16_t)a[2], (bf16_t)a[3],
                 (bf16_t)b[0], (bf16_t)b[1], (bf16_t)b[2], (bf16_t)b[3] };
    return r;
}
__device__ inline bf16x8 ld8(const bf16_t* p) {
    return *reinterpret_cast<const bf16x8*>(p);
}

// ---------------- GEMM: C = A * B^T (+bias); A/B fp32 or bf16, converted during staging ----------------
// 64x64 tile, BK=64, 4 waves, software-pipelined staging (load k+1 to regs under MFMA of k).
template <typename AT, typename BT, typename OUT_T, bool HAS_BIAS>
__global__ __launch_bounds__(256) void gemm_bt(
    const AT* __restrict__ A, const BT* __restrict__ B,
    OUT_T* __restrict__ C, const float* __restrict__ bias,
    int K, int lda, int ldb, int ldc)
{
    const int m0 = blockIdx.x * 64;
    const int n0 = blockIdx.y * 64;

    __shared__ __align__(16) bf16_t As[64][72];   // +8 pad -> 2-way bank alias (free)
    __shared__ __align__(16) bf16_t Bs[64][72];

    const int tid  = threadIdx.x;
    const int lane = tid & 63;
    const int wave = tid >> 6;
    const int srow = tid >> 3;          // 0..31 (second chunk: +32)
    const int soff = (tid & 7) * 8;     // 0,8,..,56

    bf16x8 rA0, rA1, rB0, rB1;
    rA0 = ld8(&A[(long)(m0 + srow)      * lda + soff]);
    rA1 = ld8(&A[(long)(m0 + srow + 32) * lda + soff]);
    rB0 = ld8(&B[(long)(n0 + srow)      * ldb + soff]);
    rB1 = ld8(&B[(long)(n0 + srow + 32) * ldb + soff]);

    f32x4 acc[4] = {};

    for (int k0 = 0; k0 < K; k0 += 64) {
        *reinterpret_cast<bf16x8*>(&As[srow][soff])      = rA0;
        *reinterpret_cast<bf16x8*>(&As[srow + 32][soff]) = rA1;
        *reinterpret_cast<bf16x8*>(&Bs[srow][soff])      = rB0;
        *reinterpret_cast<bf16x8*>(&Bs[srow + 32][soff]) = rB1;
        __syncthreads();

        if (k0 + 64 < K) {              // issue next-tile loads; consumed after next barrier
            rA0 = ld8(&A[(long)(m0 + srow)      * lda + k0 + 64 + soff]);
            rA1 = ld8(&A[(long)(m0 + srow + 32) * lda + k0 + 64 + soff]);
            rB0 = ld8(&B[(long)(n0 + srow)      * ldb + k0 + 64 + soff]);
            rB1 = ld8(&B[(long)(n0 + srow + 32) * ldb + k0 + 64 + soff]);
        }

#pragma unroll
        for (int ks = 0; ks < 64; ks += 32) {
            bf16x8 af = *reinterpret_cast<const bf16x8*>(&As[wave * 16 + (lane & 15)][(lane >> 4) * 8 + ks]);
#pragma unroll
            for (int nf = 0; nf < 4; ++nf) {
                bf16x8 bfr = *reinterpret_cast<const bf16x8*>(&Bs[nf * 16 + (lane & 15)][(lane >> 4) * 8 + ks]);
                acc[nf] = __builtin_amdgcn_mfma_f32_16x16x32_bf16(af, bfr, acc[nf], 0, 0, 0);
            }
        }
        __syncthreads();
    }

    const int crow0 = m0 + wave * 16 + (lane >> 4) * 4;
    const int ccol0 = n0 + (lane & 15);
#pragma unroll
    for (int nf = 0; nf < 4; ++nf) {
        const int col = ccol0 + nf * 16;
        const float bv = HAS_BIAS ? bias[col] : 0.0f;
#pragma unroll
        for (int v = 0; v < 4; ++v) {
            C[(long)(crow0 + v) * ldc + col] = (OUT_T)(acc[nf][v] + bv);
        }
    }
}

// ---------------- fused S = softmax((q/8) k^T): one block = 64 rows x 256 cols of one (b,h) ----------------
__global__ __launch_bounds__(256) void qk_softmax(
    const bf16_t* __restrict__ qkv,   // [B,256,2304]
    float* __restrict__ probs)        // [24,256,256]
{
    const int bh = blockIdx.y;
    const int b = bh / 12, h = bh % 12;
    const int m0 = blockIdx.x * 64;
    const bf16_t* qbase = qkv + (long)b * 589824 + h * 64;
    const bf16_t* kbase = qkv + (long)b * 589824 + 768 + h * 64;

    __shared__ __align__(16) bf16_t Qs[64][72];
    __shared__ __align__(16) bf16_t Ks[256][72];

    const int t = threadIdx.x;
#pragma unroll
    for (int c = 0; c < 2; ++c) {
        const int chunk = c * 256 + t;
        const int row = chunk >> 3, off = (chunk & 7) * 8;
        *reinterpret_cast<uint4*>(&Qs[row][off]) =
            *reinterpret_cast<const uint4*>(qbase + (long)(m0 + row) * 2304 + off);
    }
#pragma unroll
    for (int c = 0; c < 8; ++c) {
        const int chunk = c * 256 + t;
        const int row = chunk >> 3, off = (chunk & 7) * 8;
        *reinterpret_cast<uint4*>(&Ks[row][off]) =
            *reinterpret_cast<const uint4*>(kbase + (long)row * 2304 + off);
    }
    __syncthreads();

    const int lane = t & 63, wave = t >> 6;
    f32x4 acc[16] = {};
#pragma unroll
    for (int ks = 0; ks < 64; ks += 32) {
        bf16x8 af = *reinterpret_cast<const bf16x8*>(&Qs[wave * 16 + (lane & 15)][(lane >> 4) * 8 + ks]);
#pragma unroll
        for (int nf = 0; nf < 16; ++nf) {
            bf16x8 bfr = *reinterpret_cast<const bf16x8*>(&Ks[nf * 16 + (lane & 15)][(lane >> 4) * 8 + ks]);
            acc[nf] = __builtin_amdgcn_mfma_f32_16x16x32_bf16(af, bfr, acc[nf], 0, 0, 0);
        }
    }

    float inv[4];
#pragma unroll
    for (int v = 0; v < 4; ++v) {
        float mm = -1e30f;
#pragma unroll
        for (int nf = 0; nf < 16; ++nf) { acc[nf][v] *= 0.125f; mm = fmaxf(mm, acc[nf][v]); }
#pragma unroll
        for (int o = 1; o < 16; o <<= 1) mm = fmaxf(mm, __shfl_xor(mm, o));
        float s = 0.0f;
#pragma unroll
        for (int nf = 0; nf < 16; ++nf) { float e = __expf(acc[nf][v] - mm); acc[nf][v] = e; s += e; }
#pragma unroll
        for (int o = 1; o < 16; o <<= 1) s += __shfl_xor(s, o);
        inv[v] = 1.0f / s;
    }

    float* prow = probs + ((long)bh * 256 + m0 + wave * 16 + (lane >> 4) * 4) * 256 + (lane & 15);
#pragma unroll
    for (int nf = 0; nf < 16; ++nf) {
#pragma unroll
        for (int v = 0; v < 4; ++v) {
            prow[(long)v * 256 + nf * 16] = acc[nf][v] * inv[v];
        }
    }
}

// ---------------- fused: oh[b,i,c] = sum_j attn * (v + d)  (roofline-verified: ~62.5us) ----------------
__global__ __launch_bounds__(256) void attnd_kernel(
    const float* __restrict__ attn,   // [24,256,256]
    const bf16_t* __restrict__ qkv,   // [B,256,2304]
    const float* __restrict__ d,      // [B,256,256,768]
    bf16_t* __restrict__ oh)          // [B,256,768]
{
    const int bi = blockIdx.x;
    const int b  = bi >> 8;
    const int i  = bi & 255;
    const int cc = blockIdx.y;
    const int t  = threadIdx.x;
    const int lane = t & 63, wave = t >> 6;

    __shared__ float attn_s[4 * 257];
    __shared__ f32x4 partial[3][64];

#pragma unroll
    for (int q = 0; q < 4; ++q) {
        attn_s[q * 257 + t] = attn[(((long)(b * 12 + cc * 4 + q)) * 256 + i) * 256 + t];
    }
    __syncthreads();

    const int c0 = cc * 256 + lane * 4;
    const float* arow = attn_s + (lane >> 4) * 257;
    const int jb = wave * 64;
    const f32x4* dp = reinterpret_cast<const f32x4*>(d + (long)bi * 196608 + (long)jb * 768 + c0);
    const bf16_t* vp = qkv + (long)b * 589824 + (long)jb * 2304 + 1536 + c0;

    f32x4 acc = {};
#pragma unroll 8
    for (int jj = 0; jj < 64; ++jj) {
        f32x4 dv = __builtin_nontemporal_load(dp + (long)jj * 192);
        bf16x4 vv = *reinterpret_cast<const bf16x4*>(vp + (long)jj * 2304);
        float a = arow[jb + jj];
        acc[0] = fmaf(a, dv[0] + (float)vv[0], acc[0]);
        acc[1] = fmaf(a, dv[1] + (float)vv[1], acc[1]);
        acc[2] = fmaf(a, dv[2] + (float)vv[2], acc[2]);
        acc[3] = fmaf(a, dv[3] + (float)vv[3], acc[3]);
    }

    if (wave) partial[wave - 1][lane] = acc;
    __syncthreads();
    if (wave == 0) {
        acc += partial[0][lane] + partial[1][lane] + partial[2][lane];
        bf16x4 o = { (bf16_t)acc[0], (bf16_t)acc[1], (bf16_t)acc[2], (bf16_t)acc[3] };
        *reinterpret_cast<bf16x4*>(oh + (long)bi * 768 + c0) = o;
    }
}

// ---------------- launch ----------------
extern "C" void kernel_launch(void* const* d_in, const int* in_sizes, int n_in,
                              void* d_out, int out_size, void* d_ws, size_t ws_size,
                              hipStream_t stream) {
    const float* x      = (const float*)d_in[0];   // [2,256,768]
    const float* d      = (const float*)d_in[1];   // [2,256,256,768]
    const float* w_qkv  = (const float*)d_in[2];   // [2304,768]
    const float* w_proj = (const float*)d_in[3];   // [768,768]
    const float* b_proj = (const float*)d_in[4];   // [768]
    float* out = (float*)d_out;                    // [2,256,768]

    char* ws = (char*)d_ws;
    bf16_t* qkvb  = (bf16_t*)(ws + 5505024);       //  512x2304 bf16
    float*  probs = (float*)(ws + 7864320);        //  24x256x256 fp32
    bf16_t* oh    = (bf16_t*)(ws + 14155776);      //  512x768 bf16

    // 1. qkv = x @ w_qkv^T -> bf16 [512,2304]  (fp32 inputs converted during staging)
    gemm_bt<float, float, bf16_t, false><<<dim3(8, 36), 256, 0, stream>>>(
        x, w_qkv, qkvb, nullptr, 768, 768, 768, 2304);

    // 2. probs = softmax((q/8) k^T) -> fp32 [24,256,256]
    qk_softmax<<<dim3(4, 24), 256, 0, stream>>>(qkvb, probs);

    // 3. oh = attn @ (v + d_pair) -> bf16 [512,768]
    attnd_kernel<<<dim3(512, 3), 256, 0, stream>>>(probs, qkvb, d, oh);

    // 4. out = oh @ w_proj^T + b_proj -> fp32
    gemm_bt<bf16_t, float, float, true><<<dim3(8, 12), 256, 0, stream>>>(
        oh, w_proj, out, b_proj, 768, 768, 768, 768);
}

// Round 7
// 99.975 us; speedup vs baseline: 1.8246x; 1.0306x over previous
//
#include <hip/hip_runtime.h>

typedef __bf16 bf16_t;
typedef bf16_t bf16x8 __attribute__((ext_vector_type(8)));
typedef bf16_t bf16x4 __attribute__((ext_vector_type(4)));
typedef float f32x4 __attribute__((ext_vector_type(4)));

// load 8 contiguous elements as bf16x8 (fp32 source converts in-register)
__device__ inline bf16x8 ld8(const float* p) {
    f32x4 a = *reinterpret_cast<const f32x4*>(p);
    f32x4 b = *reinterpret_cast<const f32x4*>(p + 4);
    bf16x8 r = { (bf16_t)a[0], (bf16_t)a[1], (bf16_t)a[2], (bf16_t)a[3],
                 (bf16_t)b[0], (bf16_t)b[1], (bf16_t)b[2], (bf16_t)b[3] };
    return r;
}
__device__ inline bf16x8 ld8(const bf16_t* p) {
    return *reinterpret_cast<const bf16x8*>(p);
}

// ---------------- GEMM: C = A * B^T (+bias); fp32/bf16 sources converted during staging ----------------
// 64x64 tile, BK=64, software-pipelined. 1-D grid of (8 m-tiles) x (numN n-tiles), XCD-aware remap:
// xcd = l&7 owns a contiguous slice of n-tiles -> B panels read ~once per XCD instead of 8x.
template <typename AT, typename BT, typename OUT_T, bool HAS_BIAS>
__global__ __launch_bounds__(256) void gemm_bt(
    const AT* __restrict__ A, const BT* __restrict__ B,
    OUT_T* __restrict__ C, const float* __restrict__ bias,
    int K, int lda, int ldb, int ldc)
{
    const int l  = blockIdx.x;
    const int lp = (l & 7) * (gridDim.x >> 3) + (l >> 3);   // bijective XCD chunking (total%8==0)
    const int m0 = (lp & 7) * 64;                           // 8 m-tiles (M=512)
    const int n0 = (lp >> 3) * 64;

    __shared__ __align__(16) bf16_t As[64][72];   // +8 pad -> 2-way bank alias (free)
    __shared__ __align__(16) bf16_t Bs[64][72];

    const int tid  = threadIdx.x;
    const int lane = tid & 63;
    const int wave = tid >> 6;
    const int srow = tid >> 3;          // 0..31 (second chunk: +32)
    const int soff = (tid & 7) * 8;     // 0,8,..,56

    bf16x8 rA0, rA1, rB0, rB1;
    rA0 = ld8(&A[(long)(m0 + srow)      * lda + soff]);
    rA1 = ld8(&A[(long)(m0 + srow + 32) * lda + soff]);
    rB0 = ld8(&B[(long)(n0 + srow)      * ldb + soff]);
    rB1 = ld8(&B[(long)(n0 + srow + 32) * ldb + soff]);

    f32x4 acc[4] = {};

    for (int k0 = 0; k0 < K; k0 += 64) {
        *reinterpret_cast<bf16x8*>(&As[srow][soff])      = rA0;
        *reinterpret_cast<bf16x8*>(&As[srow + 32][soff]) = rA1;
        *reinterpret_cast<bf16x8*>(&Bs[srow][soff])      = rB0;
        *reinterpret_cast<bf16x8*>(&Bs[srow + 32][soff]) = rB1;
        __syncthreads();

        if (k0 + 64 < K) {              // issue next-tile loads; consumed after next barrier
            rA0 = ld8(&A[(long)(m0 + srow)      * lda + k0 + 64 + soff]);
            rA1 = ld8(&A[(long)(m0 + srow + 32) * lda + k0 + 64 + soff]);
            rB0 = ld8(&B[(long)(n0 + srow)      * ldb + k0 + 64 + soff]);
            rB1 = ld8(&B[(long)(n0 + srow + 32) * ldb + k0 + 64 + soff]);
        }

#pragma unroll
        for (int ks = 0; ks < 64; ks += 32) {
            bf16x8 af = *reinterpret_cast<const bf16x8*>(&As[wave * 16 + (lane & 15)][(lane >> 4) * 8 + ks]);
#pragma unroll
            for (int nf = 0; nf < 4; ++nf) {
                bf16x8 bfr = *reinterpret_cast<const bf16x8*>(&Bs[nf * 16 + (lane & 15)][(lane >> 4) * 8 + ks]);
                acc[nf] = __builtin_amdgcn_mfma_f32_16x16x32_bf16(af, bfr, acc[nf], 0, 0, 0);
            }
        }
        __syncthreads();
    }

    const int crow0 = m0 + wave * 16 + (lane >> 4) * 4;
    const int ccol0 = n0 + (lane & 15);
#pragma unroll
    for (int nf = 0; nf < 4; ++nf) {
        const int col = ccol0 + nf * 16;
        const float bv = HAS_BIAS ? bias[col] : 0.0f;
#pragma unroll
        for (int v = 0; v < 4; ++v) {
            C[(long)(crow0 + v) * ldc + col] = (OUT_T)(acc[nf][v] + bv);
        }
    }
}

// ---------------- fused S = softmax((q/8) k^T): grid (24 bh, 4 m-tiles) ----------------
// bh fastest -> xcd = bh%8: all 4 m-tiles of one (b,h) share an XCD (K staged once per XCD).
__global__ __launch_bounds__(256) void qk_softmax(
    const bf16_t* __restrict__ qkv,   // [B,256,2304]
    float* __restrict__ probs)        // [24,256,256]
{
    const int bh = blockIdx.x;
    const int b = bh / 12, h = bh % 12;
    const int m0 = blockIdx.y * 64;
    const bf16_t* qbase = qkv + (long)b * 589824 + h * 64;
    const bf16_t* kbase = qkv + (long)b * 589824 + 768 + h * 64;

    __shared__ __align__(16) bf16_t Qs[64][72];
    __shared__ __align__(16) bf16_t Ks[256][72];

    const int t = threadIdx.x;
#pragma unroll
    for (int c = 0; c < 2; ++c) {
        const int chunk = c * 256 + t;
        const int row = chunk >> 3, off = (chunk & 7) * 8;
        *reinterpret_cast<uint4*>(&Qs[row][off]) =
            *reinterpret_cast<const uint4*>(qbase + (long)(m0 + row) * 2304 + off);
    }
#pragma unroll
    for (int c = 0; c < 8; ++c) {
        const int chunk = c * 256 + t;
        const int row = chunk >> 3, off = (chunk & 7) * 8;
        *reinterpret_cast<uint4*>(&Ks[row][off]) =
            *reinterpret_cast<const uint4*>(kbase + (long)row * 2304 + off);
    }
    __syncthreads();

    const int lane = t & 63, wave = t >> 6;
    f32x4 acc[16] = {};
#pragma unroll
    for (int ks = 0; ks < 64; ks += 32) {
        bf16x8 af = *reinterpret_cast<const bf16x8*>(&Qs[wave * 16 + (lane & 15)][(lane >> 4) * 8 + ks]);
#pragma unroll
        for (int nf = 0; nf < 16; ++nf) {
            bf16x8 bfr = *reinterpret_cast<const bf16x8*>(&Ks[nf * 16 + (lane & 15)][(lane >> 4) * 8 + ks]);
            acc[nf] = __builtin_amdgcn_mfma_f32_16x16x32_bf16(af, bfr, acc[nf], 0, 0, 0);
        }
    }

    float inv[4];
#pragma unroll
    for (int v = 0; v < 4; ++v) {
        float mm = -1e30f;
#pragma unroll
        for (int nf = 0; nf < 16; ++nf) { acc[nf][v] *= 0.125f; mm = fmaxf(mm, acc[nf][v]); }
#pragma unroll
        for (int o = 1; o < 16; o <<= 1) mm = fmaxf(mm, __shfl_xor(mm, o));
        float s = 0.0f;
#pragma unroll
        for (int nf = 0; nf < 16; ++nf) { float e = __expf(acc[nf][v] - mm); acc[nf][v] = e; s += e; }
#pragma unroll
        for (int o = 1; o < 16; o <<= 1) s += __shfl_xor(s, o);
        inv[v] = 1.0f / s;
    }

    float* prow = probs + ((long)bh * 256 + m0 + wave * 16 + (lane >> 4) * 4) * 256 + (lane & 15);
#pragma unroll
    for (int nf = 0; nf < 16; ++nf) {
#pragma unroll
        for (int v = 0; v < 4; ++v) {
            prow[(long)v * 256 + nf * 16] = acc[nf][v] * inv[v];
        }
    }
}

// ---------------- fused: oh[b,i,c] = sum_j attn * (v + d)  (roofline-verified: ~62.5us) ----------------
__global__ __launch_bounds__(256) void attnd_kernel(
    const float* __restrict__ attn,   // [24,256,256]
    const bf16_t* __restrict__ qkv,   // [B,256,2304]
    const float* __restrict__ d,      // [B,256,256,768]
    bf16_t* __restrict__ oh)          // [B,256,768]
{
    const int bi = blockIdx.x;
    const int b  = bi >> 8;
    const int i  = bi & 255;
    const int cc = blockIdx.y;
    const int t  = threadIdx.x;
    const int lane = t & 63, wave = t >> 6;

    __shared__ float attn_s[4 * 257];
    __shared__ f32x4 partial[3][64];

#pragma unroll
    for (int q = 0; q < 4; ++q) {
        attn_s[q * 257 + t] = attn[(((long)(b * 12 + cc * 4 + q)) * 256 + i) * 256 + t];
    }
    __syncthreads();

    const int c0 = cc * 256 + lane * 4;
    const float* arow = attn_s + (lane >> 4) * 257;
    const int jb = wave * 64;
    const f32x4* dp = reinterpret_cast<const f32x4*>(d + (long)bi * 196608 + (long)jb * 768 + c0);
    const bf16_t* vp = qkv + (long)b * 589824 + (long)jb * 2304 + 1536 + c0;

    f32x4 acc = {};
#pragma unroll 8
    for (int jj = 0; jj < 64; ++jj) {
        f32x4 dv = __builtin_nontemporal_load(dp + (long)jj * 192);
        bf16x4 vv = *reinterpret_cast<const bf16x4*>(vp + (long)jj * 2304);
        float a = arow[jb + jj];
        acc[0] = fmaf(a, dv[0] + (float)vv[0], acc[0]);
        acc[1] = fmaf(a, dv[1] + (float)vv[1], acc[1]);
        acc[2] = fmaf(a, dv[2] + (float)vv[2], acc[2]);
        acc[3] = fmaf(a, dv[3] + (float)vv[3], acc[3]);
    }

    if (wave) partial[wave - 1][lane] = acc;
    __syncthreads();
    if (wave == 0) {
        acc += partial[0][lane] + partial[1][lane] + partial[2][lane];
        bf16x4 o = { (bf16_t)acc[0], (bf16_t)acc[1], (bf16_t)acc[2], (bf16_t)acc[3] };
        *reinterpret_cast<bf16x4*>(oh + (long)bi * 768 + c0) = o;
    }
}

// ---------------- launch ----------------
extern "C" void kernel_launch(void* const* d_in, const int* in_sizes, int n_in,
                              void* d_out, int out_size, void* d_ws, size_t ws_size,
                              hipStream_t stream) {
    const float* x      = (const float*)d_in[0];   // [2,256,768]
    const float* d      = (const float*)d_in[1];   // [2,256,256,768]
    const float* w_qkv  = (const float*)d_in[2];   // [2304,768]
    const float* w_proj = (const float*)d_in[3];   // [768,768]
    const float* b_proj = (const float*)d_in[4];   // [768]
    float* out = (float*)d_out;                    // [2,256,768]

    char* ws = (char*)d_ws;
    bf16_t* qkvb  = (bf16_t*)(ws + 5505024);       //  512x2304 bf16
    float*  probs = (float*)(ws + 7864320);        //  24x256x256 fp32
    bf16_t* oh    = (bf16_t*)(ws + 14155776);      //  512x768 bf16

    // 1. qkv = x @ w_qkv^T -> bf16 [512,2304]  (288 tiles, XCD-remapped)
    gemm_bt<float, float, bf16_t, false><<<288, 256, 0, stream>>>(
        x, w_qkv, qkvb, nullptr, 768, 768, 768, 2304);

    // 2. probs = softmax((q/8) k^T) -> fp32 [24,256,256]
    qk_softmax<<<dim3(24, 4), 256, 0, stream>>>(qkvb, probs);

    // 3. oh = attn @ (v + d_pair) -> bf16 [512,768]
    attnd_kernel<<<dim3(512, 3), 256, 0, stream>>>(probs, qkvb, d, oh);

    // 4. out = oh @ w_proj^T + b_proj -> fp32  (96 tiles, XCD-remapped)
    gemm_bt<bf16_t, float, float, true><<<96, 256, 0, stream>>>(
        oh, w_proj, out, b_proj, 768, 768, 768, 768);
}